// Round 1
// baseline (65.379 us; speedup 1.0000x reference)
//
#include <hip/hip_runtime.h>
#include <math.h>

#define HID 2880
#define NE  128
#define BK  64              // k per chunk (2 x 32)
#define TOKB 64
#define NCH 45              // total chunks; 3 groups x 15
#define HN  15              // chunks per k-group
#define PSTR 129

typedef _Float16 half4v __attribute__((ext_vector_type(4)));
typedef _Float16 half8v __attribute__((ext_vector_type(8)));
typedef float    f32x4v __attribute__((ext_vector_type(4)));

// ---------------- prep: split W fp32 -> f16 hi/lo, [kt 45][sub 2][e 128][k 32] ------
__global__ __launch_bounds__(256)
void prep_w(const float* __restrict__ W, _Float16* __restrict__ whi,
            _Float16* __restrict__ wlo)
{
    const int e = blockIdx.x;
    for (int j = 0; j < 12; ++j) {
        const int k = j * 256 + threadIdx.x;
        if (k >= HID) break;
        const float v = W[(size_t)e * HID + k];
        const _Float16 h = (_Float16)v;
        const _Float16 l = (_Float16)(v - (float)h);
        const size_t idx = (size_t)(k >> 6) * 8192 + ((k >> 5) & 1) * 4096
                         + e * 32 + (k & 31);
        whi[idx] = h;
        wlo[idx] = l;
    }
}

// asm-forced 16B global load: regs cannot be collapsed/sunk; order = issue order.
#define GLOAD(dst, ptr) \
    asm volatile("global_load_dwordx4 %0, %1, off" : "=v"(dst) : "v"(ptr))

// ---------------- fused: 12-wave 3-way k-split, m=2 (48 MFMA : 16 ds_read) ----------
// grid T/64 = 256 blocks (1/CU), 768 thr (12 waves, 3/SIMD). ks = wv>>2 (k-third,
// 15 chunks), wq = wv&3 -> experts [wq*32,+32) x 64 tok. W depth-1 two-set
// alternation: step i issues A(i+1)[4]+W(i+1)[8]; vmcnt(12) retires W(i) before
// MFMA (one full step of cover); vmcnt(8) after MFMA retires A(i+1) for CONVA,
// keeping W(i+1) in flight across the lgkm-only barrier.
//
// A-tile LDS swizzle: rows are 64 B tokens (bank period = 2 rows); un-swizzled,
// the fragment read (16 tokens x same 16B k-column) is an 8-way bank conflict
// (4.76M conflict cycles measured). kbyte ^= ((tok>>1)&3)<<4 spreads the 8
// same-parity-row lanes across all four 16B columns -> free 2-way. Applied on
// BOTH the CONVA write side and the read side (same involution).
__global__ __launch_bounds__(768, 1)
void fused_router(const float* __restrict__ A, const _Float16* __restrict__ whi,
                  const _Float16* __restrict__ wlo, const float* __restrict__ bias,
                  float* __restrict__ scores, float* __restrict__ idxOut,
                  float* __restrict__ counts)
{
    // staging: [ks3][buf2][h2][sub2][64 tok][32 k] halves = 96 KB; epilogue overlay
    __shared__ __align__(16) char smem[98304];
    __shared__ float sval[TOKB][4];
    __shared__ int   sidx[TOKB][4];
    __shared__ int   hist[NE];

#define SA(ks, buf, h, sub) \
    (smem + (ks) * 32768 + ((((buf) * 2 + (h)) * 2 + (sub)) * 4096))

#define SWZ(tok) ((((tok) >> 1) & 3) << 4)

    const int tid  = threadIdx.x;
    const int lane = tid & 63;
    const int wv   = __builtin_amdgcn_readfirstlane(tid >> 6);   // 0..11
    const int ks   = wv >> 2;        // k-third 0..2
    const int wq   = wv & 3;         // expert group 0..3
    const int lg   = lane >> 4;      // k-quarter 0..3
    const int lr   = lane & 15;
    const int tokBase = blockIdx.x * TOKB;
    const int hbeg = ks * HN;

    // W per-lane fragment bases (halves): e = wq*32 + m*16 + lr, k-off lg*8
    const _Float16* wHp[2];
    const _Float16* wLp[2];
#pragma unroll
    for (int m = 0; m < 2; ++m) {
        const size_t b = (size_t)((wq * 32 + m * 16 + lr) * 32 + lg * 8);
        wHp[m] = whi + b;
        wLp[m] = wlo + b;
    }

    // A producers: per ks-group 256 threads stage 64 tok x 16 f4-slots; 4/thread
    const int gid = tid & 255;
    const float* aSrcP[4];
    int aSub[4], aWr[4];
#pragma unroll
    for (int p = 0; p < 4; ++p) {
        const int f = p * 256 + gid;
        const int tok = f >> 4, sl = f & 15;
        aSub[p] = sl >> 3;
        const int q = sl & 7;
        aSrcP[p] = A + (size_t)(tokBase + tok) * HID + aSub[p] * 32 + q * 4;
        aWr[p] = tok * 64 + ((q * 8) ^ SWZ(tok));   // swizzled byte off in tile
    }

    // A consumer byte offsets: token n*16+lr, k-quarter lg (same swizzle)
    int aRd[4];
#pragma unroll
    for (int n = 0; n < 4; ++n) {
        const int tok = n * 16 + lr;
        aRd[n] = tok * 64 + ((lg * 16) ^ SWZ(tok));
    }

    float4 aA, aB, aC, aD;
#define AISSUE(c) do {                                                         \
    GLOAD(aA, aSrcP[0] + (size_t)(c) * BK);                                    \
    GLOAD(aB, aSrcP[1] + (size_t)(c) * BK);                                    \
    GLOAD(aC, aSrcP[2] + (size_t)(c) * BK);                                    \
    GLOAD(aD, aSrcP[3] + (size_t)(c) * BK);                                    \
} while (0)

    // W set: [m*4 + s*2 + hl] -> 8 half8v = 32 VGPR forced
#define WISSUE(SET, c) do {                                                    \
    _Pragma("unroll")                                                          \
    for (int m = 0; m < 2; ++m)                                                \
        _Pragma("unroll")                                                      \
        for (int s = 0; s < 2; ++s) {                                          \
            const size_t o = (size_t)(c) * 8192 + s * 4096;                    \
            GLOAD(SET[m * 4 + s * 2 + 0], wHp[m] + o);                         \
            GLOAD(SET[m * 4 + s * 2 + 1], wLp[m] + o);                         \
        }                                                                      \
} while (0)

    auto CONVA = [&](int buf) {
#pragma unroll
        for (int p = 0; p < 4; ++p) {
            const float4 v = (p == 0) ? aA : (p == 1) ? aB : (p == 2) ? aC : aD;
            const _Float16 h0 = (_Float16)v.x, h1 = (_Float16)v.y,
                           h2 = (_Float16)v.z, h3 = (_Float16)v.w;
            const half4v hh = {h0, h1, h2, h3};
            const half4v ll = {(_Float16)(v.x - (float)h0),
                               (_Float16)(v.y - (float)h1),
                               (_Float16)(v.z - (float)h2),
                               (_Float16)(v.w - (float)h3)};
            *reinterpret_cast<half4v*>(SA(ks, buf, 0, aSub[p]) + aWr[p]) = hh;
            *reinterpret_cast<half4v*>(SA(ks, buf, 1, aSub[p]) + aWr[p]) = ll;
        }
    };

    f32x4v acc[2][4];
#pragma unroll
    for (int m = 0; m < 2; ++m)
#pragma unroll
        for (int n = 0; n < 4; ++n) acc[m][n] = (f32x4v)0.f;

    half8v wA[8], wB[8];

#define STEP(i, SU, SF) do {                                                   \
    if ((i) + 1 < HN) { AISSUE(hbeg + (i) + 1); WISSUE(SF, hbeg + (i) + 1); }  \
    __builtin_amdgcn_sched_barrier(0);                                         \
    if ((i) + 1 < HN) asm volatile("s_waitcnt vmcnt(12)" ::: "memory");        \
    else              asm volatile("s_waitcnt vmcnt(0)" ::: "memory");         \
    __builtin_amdgcn_sched_barrier(0);                                         \
    const int buf_ = (i) & 1;                                                  \
    _Pragma("unroll")                                                          \
    for (int s = 0; s < 2; ++s)                                                \
        _Pragma("unroll")                                                      \
        for (int n = 0; n < 4; ++n) {                                          \
            const half8v ah = *reinterpret_cast<const half8v*>(                \
                SA(ks, buf_, 0, s) + aRd[n]);                                  \
            const half8v al = *reinterpret_cast<const half8v*>(                \
                SA(ks, buf_, 1, s) + aRd[n]);                                  \
            _Pragma("unroll")                                                  \
            for (int m = 0; m < 2; ++m) {                                      \
                acc[m][n] = __builtin_amdgcn_mfma_f32_16x16x32_f16(            \
                    SU[m * 4 + s * 2 + 0], ah, acc[m][n], 0, 0, 0);            \
                acc[m][n] = __builtin_amdgcn_mfma_f32_16x16x32_f16(            \
                    SU[m * 4 + s * 2 + 1], ah, acc[m][n], 0, 0, 0);            \
                acc[m][n] = __builtin_amdgcn_mfma_f32_16x16x32_f16(            \
                    SU[m * 4 + s * 2 + 0], al, acc[m][n], 0, 0, 0);            \
            }                                                                  \
        }                                                                      \
    if ((i) + 1 < HN) {                                                        \
        asm volatile("s_waitcnt vmcnt(8)" ::: "memory");                       \
        __builtin_amdgcn_sched_barrier(0);                                     \
        CONVA(((i) + 1) & 1);                                                  \
    }                                                                          \
    asm volatile("s_waitcnt lgkmcnt(0)" ::: "memory");                         \
    __builtin_amdgcn_sched_barrier(0);                                         \
    __builtin_amdgcn_s_barrier();                                              \
    __builtin_amdgcn_sched_barrier(0);                                         \
} while (0)

    // prologue: A(hbeg)[4] + W(hbeg)->wA[8]; vmcnt(8) retires A; publish buf0
    AISSUE(hbeg);
    WISSUE(wA, hbeg);
    asm volatile("s_waitcnt vmcnt(8)" ::: "memory");
    __builtin_amdgcn_sched_barrier(0);
    CONVA(0);
    asm volatile("s_waitcnt lgkmcnt(0)" ::: "memory");
    __builtin_amdgcn_sched_barrier(0);
    __builtin_amdgcn_s_barrier();
    __builtin_amdgcn_sched_barrier(0);

#pragma unroll 1
    for (int i = 0; i < HN - 1; i += 2) {
        STEP(i,     wA, wB);
        STEP(i + 1, wB, wA);
    }
    STEP(HN - 1, wA, wB);     // HN odd: last chunk uses set A, no issues

    // ---------------- epilogue: deterministic 3-way reduction ----------------
    float* P1   = (float*)(smem);            // 64*129*4 = 33024 B (overlay)
    float* P2   = (float*)(smem + 33024);    // 33024 B
    float* cval = (float*)(smem + 66048);    // 64*33*4 = 8448 B
    int*   cidx = (int*)(smem + 74496);      // 8448 B

    if (tid < NE) hist[tid] = 0;

    // ks=1/2 partials -> LDS (staging dead after final barrier)
    if (ks == 1 || ks == 2) {
        float* P = (ks == 1) ? P1 : P2;
#pragma unroll
        for (int m = 0; m < 2; ++m)
#pragma unroll
            for (int n = 0; n < 4; ++n)
#pragma unroll
                for (int r = 0; r < 4; ++r) {
                    const int e = wq * 32 + m * 16 + lg * 4 + r;
                    const int t = n * 16 + lr;
                    P[t * PSTR + e] = acc[m][n][r];
                }
    }
    __syncthreads();

    // ks=0 combines in fixed order -> logits in P1
    if (ks == 0) {
#pragma unroll
        for (int m = 0; m < 2; ++m)
#pragma unroll
            for (int n = 0; n < 4; ++n)
#pragma unroll
                for (int r = 0; r < 4; ++r) {
                    const int e = wq * 32 + m * 16 + lg * 4 + r;
                    const int t = n * 16 + lr;
                    const int off = t * PSTR + e;
                    P1[off] = ((acc[m][n][r] + P1[off]) + P2[off]) + bias[e];
                }
    }
    __syncthreads();

    // top-4 candidates: 64 tok x 8 groups of 16 experts (threads 0..511)
    if (tid < 512) {
        const int t = tid & 63, g = tid >> 6;
        float v0 = -1e30f, v1 = -1e30f, v2 = -1e30f, v3 = -1e30f;
        int   i0 = 0, i1 = 0, i2 = 0, i3 = 0;
        const int e0 = g * 16;
#pragma unroll 4
        for (int i = 0; i < 16; ++i) {
            const int e = e0 + i;
            const float v = P1[t * PSTR + e];
            if (v > v3) {
                if (v > v2) {
                    v3 = v2; i3 = i2;
                    if (v > v1) {
                        v2 = v1; i2 = i1;
                        if (v > v0) { v1 = v0; i1 = i0; v0 = v; i0 = e; }
                        else        { v1 = v;  i1 = e; }
                    } else { v2 = v; i2 = e; }
                } else { v3 = v; i3 = e; }
            }
        }
        cval[t * 33 + g * 4 + 0] = v0; cidx[t * 33 + g * 4 + 0] = i0;
        cval[t * 33 + g * 4 + 1] = v1; cidx[t * 33 + g * 4 + 1] = i1;
        cval[t * 33 + g * 4 + 2] = v2; cidx[t * 33 + g * 4 + 2] = i2;
        cval[t * 33 + g * 4 + 3] = v3; cidx[t * 33 + g * 4 + 3] = i3;
    }
    __syncthreads();

    if (tid < TOKB) {
        const int t = tid;
        float m0 = -1e30f, m1 = -1e30f, m2 = -1e30f, m3 = -1e30f;
        int   j0 = 0, j1 = 0, j2 = 0, j3 = 0;
#pragma unroll
        for (int q = 0; q < 32; ++q) {   // group-major, ascending e within group
            const float v = cval[t * 33 + q];
            const int   e = cidx[t * 33 + q];
            if (v > m3) {
                if (v > m2) {
                    m3 = m2; j3 = j2;
                    if (v > m1) {
                        m2 = m1; j2 = j1;
                        if (v > m0) { m1 = m0; j1 = j0; m0 = v; j0 = e; }
                        else        { m1 = v;  j1 = e; }
                    } else { m2 = v; j2 = e; }
                } else { m3 = v; j3 = e; }
            }
        }
        const float x1 = expf(m1 - m0), x2 = expf(m2 - m0), x3 = expf(m3 - m0);
        const float inv = 1.f / (1.f + x1 + x2 + x3);
        sval[t][0] = inv;      sidx[t][0] = j0;
        sval[t][1] = x1 * inv; sidx[t][1] = j1;
        sval[t][2] = x2 * inv; sidx[t][2] = j2;
        sval[t][3] = x3 * inv; sidx[t][3] = j3;
        atomicAdd(&hist[j0], 1); atomicAdd(&hist[j1], 1);
        atomicAdd(&hist[j2], 1); atomicAdd(&hist[j3], 1);
    }
    __syncthreads();

    // dense score scatter: 64 tok x 128 exp = 8192 floats, coalesced
    const size_t sBase = (size_t)blockIdx.x * TOKB * NE;
#pragma unroll 4
    for (int it = 0; it < 11; ++it) {
        const int flat = it * 768 + tid;
        if (flat < TOKB * NE) {
            const int t = flat >> 7, e = flat & 127;
            float val = 0.f;
            val = (e == sidx[t][0]) ? sval[t][0] : val;
            val = (e == sidx[t][1]) ? sval[t][1] : val;
            val = (e == sidx[t][2]) ? sval[t][2] : val;
            val = (e == sidx[t][3]) ? sval[t][3] : val;
            scores[sBase + flat] = val;
        }
    }
    // indices as float32: 256 per block
    if (tid < TOKB * 4)
        idxOut[(size_t)blockIdx.x * TOKB * 4 + tid] =
            (float)sidx[tid >> 2][tid & 3];
    if (tid < NE) {
        const int c = hist[tid];
        if (c) atomicAdd(&counts[tid], (float)c);
    }
#undef SA
#undef SWZ
#undef AISSUE
#undef WISSUE
#undef STEP
}

extern "C" void kernel_launch(void* const* d_in, const int* in_sizes, int n_in,
                              void* d_out, int out_size, void* d_ws, size_t ws_size,
                              hipStream_t stream) {
    const float* A = (const float*)d_in[0];   // hidden_states [T, 2880]
    const float* W = (const float*)d_in[1];   // weight [128, 2880]
    const float* B = (const float*)d_in[2];   // bias [128]
    const int T = in_sizes[0] / HID;          // 16384

    float* out = (float*)d_out;
    float* scores = out;                          // [T,128]
    float* idxOut = out + (size_t)T * NE;         // [T,4] as float
    float* counts = idxOut + (size_t)T * 4;       // [128] as float

    _Float16* whi = (_Float16*)d_ws;              // [45][2][128][32] halves
    _Float16* wlo = whi + (size_t)NE * HID;

    hipMemsetAsync(counts, 0, NE * sizeof(float), stream);

    hipLaunchKernelGGL(prep_w, dim3(NE), dim3(256), 0, stream, W, whi, wlo);
    hipLaunchKernelGGL(fused_router, dim3(T / TOKB), dim3(768), 0, stream,
                       A, whi, wlo, B, scores, idxOut, counts);
}